// Round 8
// baseline (216.758 us; speedup 1.0000x reference)
//
#include <hip/hip_runtime.h>
#include <stdint.h>

#define ALPHA 0.2f
#define L2E 1.4426950408889634f

typedef __attribute__((ext_vector_type(8))) short bf16x8;
typedef __attribute__((ext_vector_type(4))) float f32x4;

__device__ __forceinline__ unsigned short f2bf(float f) {
    unsigned int u = __float_as_uint(f);
    u += 0x7fffu + ((u >> 16) & 1u);   // RNE
    return (unsigned short)(u >> 16);
}

__device__ __forceinline__ void gload_lds16(const void* g, void* l) {
    __builtin_amdgcn_global_load_lds(
        (const __attribute__((address_space(1))) unsigned int*)g,
        (__attribute__((address_space(3))) unsigned int*)l, 16, 0, 0);
}

// lgkm-only barrier: orders LDS ops across the block WITHOUT draining vmcnt —
// in-flight global loads (register B-fragments) cross it untouched.
__device__ __forceinline__ void bar_lds() {
    asm volatile("s_waitcnt lgkmcnt(0)" ::: "memory");
    __builtin_amdgcn_s_barrier();
}

// ---------------------------------------------------------------------------
// Blocks 0..255: Wtbf[o*256+t] = bf16(W[t*256+o]).
// Block 256:     wa[k] = W[k,:]·a_l ; wa[256+k] = W[k,:]·a_r  (fp32).
// ---------------------------------------------------------------------------
__global__ void wt_wa_kernel(const float* __restrict__ W,
                             const float* __restrict__ a,
                             unsigned short* __restrict__ Wtbf,
                             float* __restrict__ wa) {
    const int t = threadIdx.x;
    if (blockIdx.x < 256) {
        const int o = blockIdx.x;
        Wtbf[o * 256 + t] = f2bf(W[t * 256 + o]);
    } else {
        float sl = 0.f, sr = 0.f;
        const float* wr = W + t * 256;
        for (int o = 0; o < 256; ++o) {
            const float wv = wr[o];
            sl += wv * a[o];
            sr += wv * a[256 + o];
        }
        wa[t] = sl;
        wa[256 + t] = sr;
    }
}

// ---------------------------------------------------------------------------
// One wave per row r: el2[r] = (x[r,:]·wa_l)*log2(e), er2 likewise,
// and xbf[r,:] = bf16(x[r,:]).
// ---------------------------------------------------------------------------
__global__ __launch_bounds__(256) void eler2x_kernel(
    const float* __restrict__ x, const float* __restrict__ wa,
    float* __restrict__ el, float* __restrict__ er,
    unsigned short* __restrict__ xbf)
{
    const int w = threadIdx.x >> 6, l = threadIdx.x & 63;
    const int r = blockIdx.x * 4 + w;       // 0..16383
    const float4 xv = *(const float4*)(x + (size_t)r * 256 + l * 4);
    const float4 al = *(const float4*)(wa + l * 4);
    const float4 ar = *(const float4*)(wa + 256 + l * 4);

    ushort4 xb;
    xb.x = f2bf(xv.x); xb.y = f2bf(xv.y); xb.z = f2bf(xv.z); xb.w = f2bf(xv.w);
    *(ushort4*)(xbf + (size_t)r * 256 + l * 4) = xb;

    float sl = xv.x * al.x + xv.y * al.y + xv.z * al.z + xv.w * al.w;
    float sr = xv.x * ar.x + xv.y * ar.y + xv.z * ar.z + xv.w * ar.w;
#pragma unroll
    for (int off = 32; off >= 1; off >>= 1) {
        sl += __shfl_xor(sl, off);
        sr += __shfl_xor(sr, off);
    }
    if (l == 0) { el[r] = sl * L2E; er[r] = sr * L2E; }
}

// ---------------------------------------------------------------------------
// h_T (256 x 16384) = Wtbf (256x256) @ xbf^T.  Flat batched GEMM.
// 64(m) x 128(n) tiles, K-step 64, grid (128,4) = 512 blocks (2/CU).
// 2-phase: double-buffered LDS, counted vmcnt (loads fly across barriers).
// ---------------------------------------------------------------------------
__global__ __launch_bounds__(256) void gemm_h(
    const unsigned short* __restrict__ A,    // Wtbf 256x256
    const unsigned short* __restrict__ Bt,   // xbf 16384x256
    unsigned short* __restrict__ C)          // h_T 256x16384
{
    __shared__ __align__(16) unsigned short As[2 * 64 * 64];    // 16 KB
    __shared__ __align__(16) unsigned short Bs[2 * 128 * 64];   // 32 KB

    const int tid = threadIdx.x;
    const int w = tid >> 6, l = tid & 63;
    const int q = l >> 4, ml = l & 15;
    const int wm = (w >> 1) * 32;
    const int wn = (w & 1) * 64;
    const int m0 = blockIdx.y * 64;
    const int n0 = blockIdx.x * 128;

    f32x4 acc[2][4];
#pragma unroll
    for (int i = 0; i < 2; ++i)
#pragma unroll
        for (int j = 0; j < 4; ++j) {
            f32x4 z = {0.f, 0.f, 0.f, 0.f};
            acc[i][j] = z;
        }

#define GSTAGE(BI, K0) do {                                                   \
    _Pragma("unroll")                                                         \
    for (int c_ = 0; c_ < 2; ++c_) {                                          \
        const int cb_ = c_ * 256 + (w << 6);                                  \
        const int p_ = cb_ + l;                                               \
        const int r_ = p_ >> 3;                                               \
        const int cc_ = (p_ & 7) ^ (r_ & 7);                                  \
        gload_lds16(A + (size_t)(m0 + r_) * 256 + (K0) + cc_ * 8,             \
                    As + (BI) * 4096 + cb_ * 8);                              \
    }                                                                         \
    _Pragma("unroll")                                                         \
    for (int c_ = 0; c_ < 4; ++c_) {                                          \
        const int cb_ = c_ * 256 + (w << 6);                                  \
        const int p_ = cb_ + l;                                               \
        const int r_ = p_ >> 3;                                               \
        const int cc_ = (p_ & 7) ^ (r_ & 7);                                  \
        gload_lds16(Bt + (size_t)(n0 + r_) * 256 + (K0) + cc_ * 8,            \
                    Bs + (BI) * 8192 + cb_ * 8);                              \
    } } while (0)

    GSTAGE(0, 0);

    for (int s = 0; s < 4; ++s) {
        const int cur = s & 1;
        if (s + 1 < 4) {
            GSTAGE((s + 1) & 1, (s + 1) * 64);
            asm volatile("s_waitcnt vmcnt(6) lgkmcnt(0)" ::: "memory");
        } else {
            asm volatile("s_waitcnt vmcnt(0) lgkmcnt(0)" ::: "memory");
        }
        __builtin_amdgcn_s_barrier();
        __builtin_amdgcn_sched_barrier(0);

        const unsigned short* Ab = As + cur * 4096;
        const unsigned short* Bb = Bs + cur * 8192;
        bf16x8 aF[2][2], bF[2][4];
#pragma unroll
        for (int ks = 0; ks < 2; ++ks) {
#pragma unroll
            for (int mt = 0; mt < 2; ++mt) {
                const int mm = wm + mt * 16 + ml;
                aF[ks][mt] = *(const bf16x8*)(Ab + (mm * 8 + ((ks * 4 + q) ^ (mm & 7))) * 8);
            }
#pragma unroll
            for (int nt = 0; nt < 4; ++nt) {
                const int nn = wn + nt * 16 + ml;
                bF[ks][nt] = *(const bf16x8*)(Bb + (nn * 8 + ((ks * 4 + q) ^ (nn & 7))) * 8);
            }
        }
#pragma unroll
        for (int ks = 0; ks < 2; ++ks)
            for (int mt = 0; mt < 2; ++mt)
                for (int nt = 0; nt < 4; ++nt)
                    acc[mt][nt] = __builtin_amdgcn_mfma_f32_16x16x32_bf16(
                        aF[ks][mt], bF[ks][nt], acc[mt][nt], 0, 0, 0);

        asm volatile("s_waitcnt lgkmcnt(0)" ::: "memory");
        __builtin_amdgcn_s_barrier();
    }
#undef GSTAGE

    for (int mt = 0; mt < 2; ++mt)
        for (int nt = 0; nt < 4; ++nt) {
            const int gn = n0 + wn + nt * 16 + ml;
            for (int r = 0; r < 4; ++r) {
                const int gm = m0 + wm + mt * 16 + q * 4 + r;
                C[(size_t)gm * 16384 + gn] = f2bf(acc[mt][nt][r]);
            }
        }
}

// ---------------------------------------------------------------------------
// FUSED mask + PV, UNNORMALIZED softmax, REGISTER-DIRECT H (no Hs staging).
//   out[b,i,:] = (sum_j adj? exp2(e_ij) * h[b,j,:]) / (sum_j adj? exp2(e_ij))
//
// ROUND-8 DIAGNOSIS: r3/r5/r7 j-loops all stuck at 45-53us with MfmaUtil ~6%,
// VALUBusy ~21%, HBM ~13% -> nothing busy; the invariant was the block-wide
// vmcnt wait on the 32KB global_load_lds tile re-serialized by barriers every
// iteration (7500 cy/iter vs ~300 cy of work).  Fix: the mfma B-fragment is
// 16 CONTIGUOUS bytes of an hT row, so H goes global->REGISTERS per wave
// (plain loads; the compiler's reg-wait is per-wave, not block-wide), and the
// only barriers left are lgkm-only for the Ps double-buffer handoff — global
// loads fly across them.  Prefetch distance = one full barrier phase.
// vs round 2 (which tried this and lost): 2 blocks/CU (4 waves/SIMD, forced
// via __launch_bounds__(512,4)) and 8 loads in flight/lane, not depth-1 at
// 2 waves/SIMD.  LDS: 77KB -> ~14KB.
// Wave tile: 16m x 64o (wm = (w>>2)*16, wn = (w&3)*64); acc 16 VGPR, B-frag
// 2x32 VGPR, ~110 total.  Masks: round-7 register prologue (2 u32/thread).
// Denominator from the same bf16-rounded p' (round-6), divide at the end.
// XCD decode: b = ((bid&7)<<1)|(slot>>5): 2 batches (1 MB h) per XCD L2.
// ---------------------------------------------------------------------------
__global__ __launch_bounds__(512, 4) void maskpv_kernel(
    const int* __restrict__ adj,
    const float* __restrict__ el2,
    const float* __restrict__ er2,
    const unsigned short* __restrict__ hT,   // 256 x 16384 (row stride 16384)
    float* __restrict__ out)
{
    __shared__ float er_s[1024];                                  //  4 KB
    __shared__ float s_s[32];
    __shared__ __align__(16) unsigned short Ps[2 * 32 * 72];      //  9 KB

    const int tid = threadIdx.x;
    const int w = tid >> 6, l = tid & 63;
    const int q = l >> 4, ml = l & 15;
    const int wm = (w >> 2) * 16;       // row half: 0 | 16
    const int wn = (w & 3) * 64;        // o quarter: 0..192

    const int bid = blockIdx.x;
    const int slot = bid >> 3;                        // 0..63
    const int b = ((bid & 7) << 1) | (slot >> 5);     // 2 batches per XCD
    const int i0 = (slot & 31) * 32;

    const int ib = tid >> 4;            // P-row this thread builds (0..31)
    const int js = (tid & 15) * 4;      // col offset within 64-window
    const int rg = (b << 10) + i0 + ib;
    const float el2i = el2[rg];

    const unsigned short* hb = hT + (size_t)b * 1024;

    // B-fragment base pointers: row oc = wn + nt*16 + ml, k-offset q*8
    const unsigned short* bp[4];
#pragma unroll
    for (int nt = 0; nt < 4; ++nt)
        bp[nt] = hb + (size_t)(wn + nt * 16 + ml) * 16384 + q * 8;

    bf16x8 BA[8], BB[8];   // [ks*4+nt], two named register sets (rule #20)

#define LOADB(B, T) do {                                                      \
    _Pragma("unroll")                                                         \
    for (int nt_ = 0; nt_ < 4; ++nt_) {                                       \
        B[nt_]     = *(const bf16x8*)(bp[nt_] + (T) * 64);                    \
        B[4 + nt_] = *(const bf16x8*)(bp[nt_] + (T) * 64 + 32);               \
    } } while (0)

    // issue the t=0 B-fragments first (oldest in flight)
    LOADB(BA, 0);

    // er_s init
    *(float2*)(er_s + tid * 2) = *(const float2*)(er2 + (b << 10) + tid * 2);

    // ---- PROLOGUE: deep-pipelined adj -> mask bits in 2 registers ----
    const int* arow = adj + (size_t)rg * 1024;
    unsigned mw0 = 0, mw1 = 0;
    {
        int4 av[8];
#pragma unroll
        for (int i = 0; i < 8; ++i)
            av[i] = *(const int4*)(arow + i * 64 + js);
#pragma unroll
        for (int i = 0; i < 8; ++i) {
            const unsigned bits =
                (av[i].x > 0 ? 1u : 0u) | (av[i].y > 0 ? 2u : 0u) |
                (av[i].z > 0 ? 4u : 0u) | (av[i].w > 0 ? 8u : 0u);
            mw0 |= bits << (i * 4);
        }
#pragma unroll
        for (int i = 0; i < 8; ++i)
            av[i] = *(const int4*)(arow + (i + 8) * 64 + js);
#pragma unroll
        for (int i = 0; i < 8; ++i) {
            const unsigned bits =
                (av[i].x > 0 ? 1u : 0u) | (av[i].y > 0 ? 2u : 0u) |
                (av[i].z > 0 ? 4u : 0u) | (av[i].w > 0 ? 8u : 0u);
            mw1 |= bits << (i * 4);
        }
    }

    bar_lds();   // er_s visible; B/adj loads still in flight (per-wave waits)

    f32x4 acc[4];
#pragma unroll
    for (int j = 0; j < 4; ++j) {
        f32x4 z = {0.f, 0.f, 0.f, 0.f};
        acc[j] = z;
    }
    float s0 = 0.f, s1 = 0.f, s2 = 0.f, s3 = 0.f;

// build P' = masked exp2(e) for step T into Ps[BI]; accumulate denominator
// from the SAME bf16-rounded values (masked entries contribute exactly 0)
#define BUILDP(BI, T) do {                                                    \
    const float4 ev_ = *(const float4*)(er_s + (T) * 64 + js);                \
    const unsigned mv_ =                                                      \
        (((T) < 8) ? (mw0 >> ((T) * 4)) : (mw1 >> (((T) - 8) * 4))) & 0xFu;   \
    float e0_ = el2i + ev_.x; e0_ = fmaxf(e0_, ALPHA * e0_);                  \
    float e1_ = el2i + ev_.y; e1_ = fmaxf(e1_, ALPHA * e1_);                  \
    float e2_ = el2i + ev_.z; e2_ = fmaxf(e2_, ALPHA * e2_);                  \
    float e3_ = el2i + ev_.w; e3_ = fmaxf(e3_, ALPHA * e3_);                  \
    ushort4 pv_;                                                              \
    pv_.x = (mv_ & 1u) ? f2bf(exp2f(e0_)) : (unsigned short)0;                \
    pv_.y = (mv_ & 2u) ? f2bf(exp2f(e1_)) : (unsigned short)0;                \
    pv_.z = (mv_ & 4u) ? f2bf(exp2f(e2_)) : (unsigned short)0;                \
    pv_.w = (mv_ & 8u) ? f2bf(exp2f(e3_)) : (unsigned short)0;                \
    s0 += __uint_as_float((unsigned)pv_.x << 16);                             \
    s1 += __uint_as_float((unsigned)pv_.y << 16);                             \
    s2 += __uint_as_float((unsigned)pv_.z << 16);                             \
    s3 += __uint_as_float((unsigned)pv_.w << 16);                             \
    *(ushort4*)(Ps + (BI) * 2304 + ib * 72 + js) = pv_;                       \
    } while (0)

#define COMPUTE(BI, B) do {                                                   \
    bf16x8 aF_[2];                                                            \
    _Pragma("unroll")                                                         \
    for (int ks_ = 0; ks_ < 2; ++ks_)                                         \
        aF_[ks_] = *(const bf16x8*)(Ps + (BI) * 2304 +                        \
                                    (wm + ml) * 72 + ks_ * 32 + q * 8);       \
    __builtin_amdgcn_s_setprio(1);                                            \
    _Pragma("unroll")                                                         \
    for (int ks_ = 0; ks_ < 2; ++ks_)                                         \
        _Pragma("unroll")                                                     \
        for (int nt_ = 0; nt_ < 4; ++nt_)                                     \
            acc[nt_] = __builtin_amdgcn_mfma_f32_16x16x32_bf16(               \
                aF_[ks_], B[ks_ * 4 + nt_], acc[nt_], 0, 0, 0);               \
    __builtin_amdgcn_s_setprio(0);                                            \
    } while (0)

    BUILDP(0, 0);

    for (int t = 0; t < 16; t += 2) {
        LOADB(BB, t + 1);                 // B(t+1) in flight across barriers
        BUILDP(1, t + 1);                 // write Ps[1]
        bar_lds();                        // Ps writes visible (lgkm only)
        COMPUTE(0, BA);                   // reg-wait on BA is per-wave
        bar_lds();                        // Ps[0] consumed
        if (t + 2 < 16) {
            LOADB(BA, t + 2);
            BUILDP(0, t + 2);
        }
        bar_lds();
        COMPUTE(1, BB);
        bar_lds();
    }

#undef LOADB
#undef BUILDP
#undef COMPUTE

    // ---- denominator: 16 threads per row -> s_s[ib] ----
    float ssum = (s0 + s1) + (s2 + s3);
#pragma unroll
    for (int off = 1; off <= 8; off <<= 1) ssum += __shfl_xor(ssum, off);
    if ((tid & 15) == 0) s_s[ib] = ssum;
    __syncthreads();

    // D layout: col=lane&15, row=(lane>>4)*4+reg.  Scale by 1/s, store.
    float* ob = out + (size_t)b * 262144;
    float rinv[4];
#pragma unroll
    for (int r = 0; r < 4; ++r) rinv[r] = 1.0f / s_s[wm + q * 4 + r];
#pragma unroll
    for (int nt = 0; nt < 4; ++nt) {
        const int gn = wn + nt * 16 + ml;
#pragma unroll
        for (int r = 0; r < 4; ++r) {
            const int gm = i0 + wm + q * 4 + r;
            ob[(size_t)gm * 256 + gn] = acc[nt][r] * rinv[r];
        }
    }
}

// ---------------------------------------------------------------------------
// Workspace (~17 MB):
//   Wtbf (bf16) @ 0        : 131072
//   wa   (f32)  @ 131072   : 2048
//   xbf  (bf16) @ 133120   : 8388608   (16384 x 256)
//   h_T  (bf16) @ 8521728  : 8388608   (256 x 16384)
//   el2  (f32)  @ 16910336 : 65536    (log2-scaled)
//   er2  (f32)  @ 16975872 : 65536    (log2-scaled)
// ---------------------------------------------------------------------------
extern "C" void kernel_launch(void* const* d_in, const int* in_sizes, int n_in,
                              void* d_out, int out_size, void* d_ws, size_t ws_size,
                              hipStream_t stream) {
    const float* x   = (const float*)d_in[0];   // (16,1024,256) fp32
    const int*   adj = (const int*)d_in[1];     // (16,1024,1024) int32
    const float* W   = (const float*)d_in[2];   // (256,256) fp32
    const float* a   = (const float*)d_in[3];   // (512,1) fp32
    float* out = (float*)d_out;                 // (16,1024,256) fp32

    char* ws = (char*)d_ws;
    unsigned short* Wtbf  = (unsigned short*)(ws);
    float* wa             = (float*)(ws + 131072);
    unsigned short* xbf   = (unsigned short*)(ws + 133120);
    unsigned short* h_T   = (unsigned short*)(ws + 8521728);
    float* el             = (float*)(ws + 16910336);
    float* er             = (float*)(ws + 16975872);

    wt_wa_kernel<<<dim3(257), dim3(256), 0, stream>>>(W, a, Wtbf, wa);

    eler2x_kernel<<<dim3(4096), dim3(256), 0, stream>>>(x, wa, el, er, xbf);

    // h_T (256 x 16384) = Wtbf @ xbf^T
    gemm_h<<<dim3(128, 4), dim3(256), 0, stream>>>(Wtbf, xbf, h_T);

    maskpv_kernel<<<dim3(512), dim3(512), 0, stream>>>(adj, el, er, h_T, out);
}

// Round 9
// 193.741 us; speedup vs baseline: 1.1188x; 1.1188x over previous
//
#include <hip/hip_runtime.h>
#include <stdint.h>

#define ALPHA 0.2f
#define L2E 1.4426950408889634f

typedef __attribute__((ext_vector_type(8))) short bf16x8;
typedef __attribute__((ext_vector_type(4))) float f32x4;

__device__ __forceinline__ unsigned short f2bf(float f) {
    unsigned int u = __float_as_uint(f);
    u += 0x7fffu + ((u >> 16) & 1u);   // RNE
    return (unsigned short)(u >> 16);
}

__device__ __forceinline__ void gload_lds16(const void* g, void* l) {
    __builtin_amdgcn_global_load_lds(
        (const __attribute__((address_space(1))) unsigned int*)g,
        (__attribute__((address_space(3))) unsigned int*)l, 16, 0, 0);
}

// ---------------------------------------------------------------------------
// Blocks 0..255: Wtbf[o*256+t] = bf16(W[t*256+o]).
// Block 256:     wa[k] = W[k,:]·a_l ; wa[256+k] = W[k,:]·a_r  (fp32).
// ---------------------------------------------------------------------------
__global__ void wt_wa_kernel(const float* __restrict__ W,
                             const float* __restrict__ a,
                             unsigned short* __restrict__ Wtbf,
                             float* __restrict__ wa) {
    const int t = threadIdx.x;
    if (blockIdx.x < 256) {
        const int o = blockIdx.x;
        Wtbf[o * 256 + t] = f2bf(W[t * 256 + o]);
    } else {
        float sl = 0.f, sr = 0.f;
        const float* wr = W + t * 256;
        for (int o = 0; o < 256; ++o) {
            const float wv = wr[o];
            sl += wv * a[o];
            sr += wv * a[256 + o];
        }
        wa[t] = sl;
        wa[256 + t] = sr;
    }
}

// ---------------------------------------------------------------------------
// One wave per row r: el2[r] = (x[r,:]·wa_l)*log2(e), er2 likewise,
// and xbf[r,:] = bf16(x[r,:]).
// ---------------------------------------------------------------------------
__global__ __launch_bounds__(256) void eler2x_kernel(
    const float* __restrict__ x, const float* __restrict__ wa,
    float* __restrict__ el, float* __restrict__ er,
    unsigned short* __restrict__ xbf)
{
    const int w = threadIdx.x >> 6, l = threadIdx.x & 63;
    const int r = blockIdx.x * 4 + w;       // 0..16383
    const float4 xv = *(const float4*)(x + (size_t)r * 256 + l * 4);
    const float4 al = *(const float4*)(wa + l * 4);
    const float4 ar = *(const float4*)(wa + 256 + l * 4);

    ushort4 xb;
    xb.x = f2bf(xv.x); xb.y = f2bf(xv.y); xb.z = f2bf(xv.z); xb.w = f2bf(xv.w);
    *(ushort4*)(xbf + (size_t)r * 256 + l * 4) = xb;

    float sl = xv.x * al.x + xv.y * al.y + xv.z * al.z + xv.w * al.w;
    float sr = xv.x * ar.x + xv.y * ar.y + xv.z * ar.z + xv.w * ar.w;
#pragma unroll
    for (int off = 32; off >= 1; off >>= 1) {
        sl += __shfl_xor(sl, off);
        sr += __shfl_xor(sr, off);
    }
    if (l == 0) { el[r] = sl * L2E; er[r] = sr * L2E; }
}

// ---------------------------------------------------------------------------
// h_T (256 x 16384) = Wtbf (256x256) @ xbf^T.  Flat batched GEMM.
// 64(m) x 128(n) tiles, K-step 64, grid (128,4) = 512 blocks (2/CU).
// 2-phase: double-buffered LDS, counted vmcnt (loads fly across barriers).
// ---------------------------------------------------------------------------
__global__ __launch_bounds__(256) void gemm_h(
    const unsigned short* __restrict__ A,    // Wtbf 256x256
    const unsigned short* __restrict__ Bt,   // xbf 16384x256
    unsigned short* __restrict__ C)          // h_T 256x16384
{
    __shared__ __align__(16) unsigned short As[2 * 64 * 64];    // 16 KB
    __shared__ __align__(16) unsigned short Bs[2 * 128 * 64];   // 32 KB

    const int tid = threadIdx.x;
    const int w = tid >> 6, l = tid & 63;
    const int q = l >> 4, ml = l & 15;
    const int wm = (w >> 1) * 32;
    const int wn = (w & 1) * 64;
    const int m0 = blockIdx.y * 64;
    const int n0 = blockIdx.x * 128;

    f32x4 acc[2][4];
#pragma unroll
    for (int i = 0; i < 2; ++i)
#pragma unroll
        for (int j = 0; j < 4; ++j) {
            f32x4 z = {0.f, 0.f, 0.f, 0.f};
            acc[i][j] = z;
        }

#define GSTAGE(BI, K0) do {                                                   \
    _Pragma("unroll")                                                         \
    for (int c_ = 0; c_ < 2; ++c_) {                                          \
        const int cb_ = c_ * 256 + (w << 6);                                  \
        const int p_ = cb_ + l;                                               \
        const int r_ = p_ >> 3;                                               \
        const int cc_ = (p_ & 7) ^ (r_ & 7);                                  \
        gload_lds16(A + (size_t)(m0 + r_) * 256 + (K0) + cc_ * 8,             \
                    As + (BI) * 4096 + cb_ * 8);                              \
    }                                                                         \
    _Pragma("unroll")                                                         \
    for (int c_ = 0; c_ < 4; ++c_) {                                          \
        const int cb_ = c_ * 256 + (w << 6);                                  \
        const int p_ = cb_ + l;                                               \
        const int r_ = p_ >> 3;                                               \
        const int cc_ = (p_ & 7) ^ (r_ & 7);                                  \
        gload_lds16(Bt + (size_t)(n0 + r_) * 256 + (K0) + cc_ * 8,            \
                    Bs + (BI) * 8192 + cb_ * 8);                              \
    } } while (0)

    GSTAGE(0, 0);

    for (int s = 0; s < 4; ++s) {
        const int cur = s & 1;
        if (s + 1 < 4) {
            GSTAGE((s + 1) & 1, (s + 1) * 64);
            asm volatile("s_waitcnt vmcnt(6) lgkmcnt(0)" ::: "memory");
        } else {
            asm volatile("s_waitcnt vmcnt(0) lgkmcnt(0)" ::: "memory");
        }
        __builtin_amdgcn_s_barrier();
        __builtin_amdgcn_sched_barrier(0);

        const unsigned short* Ab = As + cur * 4096;
        const unsigned short* Bb = Bs + cur * 8192;
        bf16x8 aF[2][2], bF[2][4];
#pragma unroll
        for (int ks = 0; ks < 2; ++ks) {
#pragma unroll
            for (int mt = 0; mt < 2; ++mt) {
                const int mm = wm + mt * 16 + ml;
                aF[ks][mt] = *(const bf16x8*)(Ab + (mm * 8 + ((ks * 4 + q) ^ (mm & 7))) * 8);
            }
#pragma unroll
            for (int nt = 0; nt < 4; ++nt) {
                const int nn = wn + nt * 16 + ml;
                bF[ks][nt] = *(const bf16x8*)(Bb + (nn * 8 + ((ks * 4 + q) ^ (nn & 7))) * 8);
            }
        }
#pragma unroll
        for (int ks = 0; ks < 2; ++ks)
            for (int mt = 0; mt < 2; ++mt)
                for (int nt = 0; nt < 4; ++nt)
                    acc[mt][nt] = __builtin_amdgcn_mfma_f32_16x16x32_bf16(
                        aF[ks][mt], bF[ks][nt], acc[mt][nt], 0, 0, 0);

        asm volatile("s_waitcnt lgkmcnt(0)" ::: "memory");
        __builtin_amdgcn_s_barrier();
    }
#undef GSTAGE

    for (int mt = 0; mt < 2; ++mt)
        for (int nt = 0; nt < 4; ++nt) {
            const int gn = n0 + wn + nt * 16 + ml;
            for (int r = 0; r < 4; ++r) {
                const int gm = m0 + wm + mt * 16 + q * 4 + r;
                C[(size_t)gm * 16384 + gn] = f2bf(acc[mt][nt][r]);
            }
        }
}

// ---------------------------------------------------------------------------
// FUSED mask + PV: BARRIER-FREE hot loop, per-lane register A-fragments.
//   out[b,i,:] = (sum_j adj? exp2(e_ij) * h[b,j,:]) / (sum_j adj? exp2(e_ij))
//
// ROUND-9: r3/r5/r7 (LDS-staged, barrier-coupled) all ~46-53us with nothing
// busy; r8 (reg-direct B) was right but __launch_bounds__(512,4) + 2x B
// buffers spilled (VGPR=64, WRITE_SIZE 16->82MB, 106us).  This version keeps
// reg-direct B with a ~110-VGPR footprint and removes the LAST block-wide
// structure: the mfma A-fragment for lane (q,ml) is A[row=ml][k=q*8..+7], so
// each lane BUILDS its own A-fragment in registers (masked exp2 over its own
// j-slots) — no P tile in LDS, no barriers in the loop.  Mask bits come from
// pk_s (4.3KB bit-table, one coalesced adj pass + one barrier; [32][17]
// padding -> conflict-free b64 reads); er_s reads are broadcast.  P-build is
// replicated x4 across o-quarter waves (~6us VALU) - the price of full wave
// independence.  Denominator: each lane sums its own bf16-rounded p' (lanes'
// j-patterns partition the row), shfl over q, one end barrier.
// Single Bv[8] buffer + unroll 4 -> compiler pipelines within the cap.
// XCD decode: b = ((bid&7)<<1)|(slot>>5): 2 batches (1 MB h) per XCD L2.
// ---------------------------------------------------------------------------
__global__ __launch_bounds__(512, 4) void maskpv_kernel(
    const int* __restrict__ adj,
    const float* __restrict__ el2,
    const float* __restrict__ er2,
    const unsigned short* __restrict__ hT,   // 256 x 16384 (row stride 16384)
    float* __restrict__ out)
{
    __shared__ float er_s[1024];              //  4 KB
    __shared__ uint2 pk_s[32][17];            //  4.25 KB (pad 17: no conflicts)
    __shared__ float s_s[32];

    const int tid = threadIdx.x;
    const int w = tid >> 6, l = tid & 63;
    const int q = l >> 4, ml = l & 15;
    const int q8 = q * 8;
    const int wm = (w >> 2) * 16;       // row half: 0 | 16
    const int wn = (w & 3) * 64;        // o quarter: 0..192

    const int bid = blockIdx.x;
    const int slot = bid >> 3;                        // 0..63
    const int b = ((bid & 7) << 1) | (slot >> 5);     // 2 batches per XCD
    const int i0 = (slot & 31) * 32;

    // ---- er_s ----
    *(float2*)(er_s + tid * 2) = *(const float2*)(er2 + (b << 10) + tid * 2);

    // ---- adj -> pk_s bit-table: thread (row ib2, 64-col window t16) ----
    {
        const int ib2 = tid >> 4, t16 = tid & 15;
        const int* arow = adj + (size_t)((b << 10) + i0 + ib2) * 1024 + t16 * 64;
        unsigned lo = 0, hi = 0;
        int4 av[8];
#pragma unroll
        for (int i = 0; i < 8; ++i) av[i] = *(const int4*)(arow + i * 4);
#pragma unroll
        for (int i = 0; i < 8; ++i) {
            lo |= (av[i].x > 0 ? 1u : 0u) << (i * 4);
            lo |= (av[i].y > 0 ? 2u : 0u) << (i * 4);
            lo |= (av[i].z > 0 ? 4u : 0u) << (i * 4);
            lo |= (av[i].w > 0 ? 8u : 0u) << (i * 4);
        }
#pragma unroll
        for (int i = 0; i < 8; ++i) av[i] = *(const int4*)(arow + 32 + i * 4);
#pragma unroll
        for (int i = 0; i < 8; ++i) {
            hi |= (av[i].x > 0 ? 1u : 0u) << (i * 4);
            hi |= (av[i].y > 0 ? 2u : 0u) << (i * 4);
            hi |= (av[i].z > 0 ? 4u : 0u) << (i * 4);
            hi |= (av[i].w > 0 ? 8u : 0u) << (i * 4);
        }
        pk_s[ib2][t16] = make_uint2(lo, hi);
    }
    __syncthreads();          // once; loop below has NO barriers

    const float el2i = el2[(b << 10) + i0 + wm + ml];

    const unsigned short* hb = hT + (size_t)b * 1024;
    const unsigned short* bp[4];
#pragma unroll
    for (int nt = 0; nt < 4; ++nt)
        bp[nt] = hb + (size_t)(wn + nt * 16 + ml) * 16384 + q8;

    f32x4 acc[4];
#pragma unroll
    for (int j = 0; j < 4; ++j) {
        f32x4 z = {0.f, 0.f, 0.f, 0.f};
        acc[j] = z;
    }
    float sden = 0.f;

    union U8 { unsigned short s[8]; bf16x8 v; };

// one P' element: e=lrelu(el+er), p'=mask?exp2(e):0, bf16-round, accumulate
// the denominator from the SAME rounded value (numerator/denominator match)
#define PEL(dst, ev, bit, msk) do {                                           \
    float e_ = el2i + (ev); e_ = fmaxf(e_, ALPHA * e_);                       \
    const unsigned short pb_ =                                                \
        (((msk) >> (bit)) & 1u) ? f2bf(exp2f(e_)) : (unsigned short)0;        \
    (dst) = pb_;                                                              \
    sden += __uint_as_float((unsigned)pb_ << 16);                             \
    } while (0)

#define BUILD8(U, e0v, e1v, mv) do {                                          \
    PEL(U.s[0], (e0v).x, 0, mv); PEL(U.s[1], (e0v).y, 1, mv);                 \
    PEL(U.s[2], (e0v).z, 2, mv); PEL(U.s[3], (e0v).w, 3, mv);                 \
    PEL(U.s[4], (e1v).x, 4, mv); PEL(U.s[5], (e1v).y, 5, mv);                 \
    PEL(U.s[6], (e1v).z, 6, mv); PEL(U.s[7], (e1v).w, 7, mv);                 \
    } while (0)

#pragma unroll 4
    for (int t = 0; t < 16; ++t) {
        // B-fragments straight from global (L2/L1-resident h panel);
        // latency self-hidden under the ~120-op A-build below + TLP.
        bf16x8 Bv[8];
#pragma unroll
        for (int nt = 0; nt < 4; ++nt) {
            Bv[nt]     = *(const bf16x8*)(bp[nt] + t * 64);
            Bv[4 + nt] = *(const bf16x8*)(bp[nt] + t * 64 + 32);
        }
        // my row's mask word for this 64-col window (b64 broadcast read)
        const uint2 pw = pk_s[wm + ml][t];
        const unsigned mv0 = (pw.x >> q8) & 0xFFu;
        const unsigned mv1 = (pw.y >> q8) & 0xFFu;
        // er slices (broadcast within each 16-lane group)
        const float4 ea0 = *(const float4*)(er_s + t * 64 + q8);
        const float4 ea1 = *(const float4*)(er_s + t * 64 + q8 + 4);
        const float4 eb0 = *(const float4*)(er_s + t * 64 + 32 + q8);
        const float4 eb1 = *(const float4*)(er_s + t * 64 + 32 + q8 + 4);

        U8 A0, A1;
        BUILD8(A0, ea0, ea1, mv0);
        BUILD8(A1, eb0, eb1, mv1);

        __builtin_amdgcn_s_setprio(1);
#pragma unroll
        for (int nt = 0; nt < 4; ++nt) {
            acc[nt] = __builtin_amdgcn_mfma_f32_16x16x32_bf16(
                A0.v, Bv[nt], acc[nt], 0, 0, 0);
            acc[nt] = __builtin_amdgcn_mfma_f32_16x16x32_bf16(
                A1.v, Bv[4 + nt], acc[nt], 0, 0, 0);
        }
        __builtin_amdgcn_s_setprio(0);
    }

#undef PEL
#undef BUILD8

    // ---- denominator: q-lanes partition the row; sum across q ----
    sden += __shfl_xor(sden, 16);
    sden += __shfl_xor(sden, 32);
    if ((w & 3) == 0 && l < 16) s_s[wm + l] = sden;   // one writer per row
    __syncthreads();

    // D layout: col=lane&15, row=(lane>>4)*4+reg.  Scale by 1/s, store.
    float* ob = out + (size_t)b * 262144;
    float rinv[4];
#pragma unroll
    for (int r = 0; r < 4; ++r) rinv[r] = 1.0f / s_s[wm + q * 4 + r];
#pragma unroll
    for (int nt = 0; nt < 4; ++nt) {
        const int gn = wn + nt * 16 + ml;
#pragma unroll
        for (int r = 0; r < 4; ++r) {
            const int gm = i0 + wm + q * 4 + r;
            ob[(size_t)gm * 256 + gn] = acc[nt][r] * rinv[r];
        }
    }
}

// ---------------------------------------------------------------------------
// Workspace (~17 MB):
//   Wtbf (bf16) @ 0        : 131072
//   wa   (f32)  @ 131072   : 2048
//   xbf  (bf16) @ 133120   : 8388608   (16384 x 256)
//   h_T  (bf16) @ 8521728  : 8388608   (256 x 16384)
//   el2  (f32)  @ 16910336 : 65536    (log2-scaled)
//   er2  (f32)  @ 16975872 : 65536    (log2-scaled)
// ---------------------------------------------------------------------------
extern "C" void kernel_launch(void* const* d_in, const int* in_sizes, int n_in,
                              void* d_out, int out_size, void* d_ws, size_t ws_size,
                              hipStream_t stream) {
    const float* x   = (const float*)d_in[0];   // (16,1024,256) fp32
    const int*   adj = (const int*)d_in[1];     // (16,1024,1024) int32
    const float* W   = (const float*)d_in[2];   // (256,256) fp32
    const float* a   = (const float*)d_in[3];   // (512,1) fp32
    float* out = (float*)d_out;                 // (16,1024,256) fp32

    char* ws = (char*)d_ws;
    unsigned short* Wtbf  = (unsigned short*)(ws);
    float* wa             = (float*)(ws + 131072);
    unsigned short* xbf   = (unsigned short*)(ws + 133120);
    unsigned short* h_T   = (unsigned short*)(ws + 8521728);
    float* el             = (float*)(ws + 16910336);
    float* er             = (float*)(ws + 16975872);

    wt_wa_kernel<<<dim3(257), dim3(256), 0, stream>>>(W, a, Wtbf, wa);

    eler2x_kernel<<<dim3(4096), dim3(256), 0, stream>>>(x, wa, el, er, xbf);

    // h_T (256 x 16384) = Wtbf @ xbf^T
    gemm_h<<<dim3(128, 4), dim3(256), 0, stream>>>(Wtbf, xbf, h_T);

    maskpv_kernel<<<dim3(512), dim3(512), 0, stream>>>(adj, el, er, h_T, out);
}

// Round 10
// 170.693 us; speedup vs baseline: 1.2699x; 1.1350x over previous
//
#include <hip/hip_runtime.h>
#include <stdint.h>

#define ALPHA 0.2f
#define L2E 1.4426950408889634f

typedef __attribute__((ext_vector_type(8))) short bf16x8;
typedef __attribute__((ext_vector_type(4))) float f32x4;

__device__ __forceinline__ unsigned short f2bf(float f) {
    unsigned int u = __float_as_uint(f);
    u += 0x7fffu + ((u >> 16) & 1u);   // RNE
    return (unsigned short)(u >> 16);
}

__device__ __forceinline__ void gload_lds16(const void* g, void* l) {
    __builtin_amdgcn_global_load_lds(
        (const __attribute__((address_space(1))) unsigned int*)g,
        (__attribute__((address_space(3))) unsigned int*)l, 16, 0, 0);
}

// ---------------------------------------------------------------------------
// Blocks 0..255: Wtbf[o*256+t] = bf16(W[t*256+o]).
// Block 256:     wa[k] = W[k,:]·a_l ; wa[256+k] = W[k,:]·a_r  (fp32).
// ---------------------------------------------------------------------------
__global__ void wt_wa_kernel(const float* __restrict__ W,
                             const float* __restrict__ a,
                             unsigned short* __restrict__ Wtbf,
                             float* __restrict__ wa) {
    const int t = threadIdx.x;
    if (blockIdx.x < 256) {
        const int o = blockIdx.x;
        Wtbf[o * 256 + t] = f2bf(W[t * 256 + o]);
    } else {
        float sl = 0.f, sr = 0.f;
        const float* wr = W + t * 256;
        for (int o = 0; o < 256; ++o) {
            const float wv = wr[o];
            sl += wv * a[o];
            sr += wv * a[256 + o];
        }
        wa[t] = sl;
        wa[256 + t] = sr;
    }
}

// ---------------------------------------------------------------------------
// One wave per row r: el2[r] = (x[r,:]·wa_l)*log2(e), er2 likewise,
// and xbf[r,:] = bf16(x[r,:]).
// ---------------------------------------------------------------------------
__global__ __launch_bounds__(256) void eler2x_kernel(
    const float* __restrict__ x, const float* __restrict__ wa,
    float* __restrict__ el, float* __restrict__ er,
    unsigned short* __restrict__ xbf)
{
    const int w = threadIdx.x >> 6, l = threadIdx.x & 63;
    const int r = blockIdx.x * 4 + w;       // 0..16383
    const float4 xv = *(const float4*)(x + (size_t)r * 256 + l * 4);
    const float4 al = *(const float4*)(wa + l * 4);
    const float4 ar = *(const float4*)(wa + 256 + l * 4);

    ushort4 xb;
    xb.x = f2bf(xv.x); xb.y = f2bf(xv.y); xb.z = f2bf(xv.z); xb.w = f2bf(xv.w);
    *(ushort4*)(xbf + (size_t)r * 256 + l * 4) = xb;

    float sl = xv.x * al.x + xv.y * al.y + xv.z * al.z + xv.w * al.w;
    float sr = xv.x * ar.x + xv.y * ar.y + xv.z * ar.z + xv.w * ar.w;
#pragma unroll
    for (int off = 32; off >= 1; off >>= 1) {
        sl += __shfl_xor(sl, off);
        sr += __shfl_xor(sr, off);
    }
    if (l == 0) { el[r] = sl * L2E; er[r] = sr * L2E; }
}

// ---------------------------------------------------------------------------
// h_T (256 x 16384) = Wtbf (256x256) @ xbf^T.  Flat batched GEMM.
// 64(m) x 128(n) tiles, K-step 64, grid (128,4) = 512 blocks (2/CU).
// 2-phase: double-buffered LDS, counted vmcnt (loads fly across barriers).
// ---------------------------------------------------------------------------
__global__ __launch_bounds__(256) void gemm_h(
    const unsigned short* __restrict__ A,    // Wtbf 256x256
    const unsigned short* __restrict__ Bt,   // xbf 16384x256
    unsigned short* __restrict__ C)          // h_T 256x16384
{
    __shared__ __align__(16) unsigned short As[2 * 64 * 64];    // 16 KB
    __shared__ __align__(16) unsigned short Bs[2 * 128 * 64];   // 32 KB

    const int tid = threadIdx.x;
    const int w = tid >> 6, l = tid & 63;
    const int q = l >> 4, ml = l & 15;
    const int wm = (w >> 1) * 32;
    const int wn = (w & 1) * 64;
    const int m0 = blockIdx.y * 64;
    const int n0 = blockIdx.x * 128;

    f32x4 acc[2][4];
#pragma unroll
    for (int i = 0; i < 2; ++i)
#pragma unroll
        for (int j = 0; j < 4; ++j) {
            f32x4 z = {0.f, 0.f, 0.f, 0.f};
            acc[i][j] = z;
        }

#define GSTAGE(BI, K0) do {                                                   \
    _Pragma("unroll")                                                         \
    for (int c_ = 0; c_ < 2; ++c_) {                                          \
        const int cb_ = c_ * 256 + (w << 6);                                  \
        const int p_ = cb_ + l;                                               \
        const int r_ = p_ >> 3;                                               \
        const int cc_ = (p_ & 7) ^ (r_ & 7);                                  \
        gload_lds16(A + (size_t)(m0 + r_) * 256 + (K0) + cc_ * 8,             \
                    As + (BI) * 4096 + cb_ * 8);                              \
    }                                                                         \
    _Pragma("unroll")                                                         \
    for (int c_ = 0; c_ < 4; ++c_) {                                          \
        const int cb_ = c_ * 256 + (w << 6);                                  \
        const int p_ = cb_ + l;                                               \
        const int r_ = p_ >> 3;                                               \
        const int cc_ = (p_ & 7) ^ (r_ & 7);                                  \
        gload_lds16(Bt + (size_t)(n0 + r_) * 256 + (K0) + cc_ * 8,            \
                    Bs + (BI) * 8192 + cb_ * 8);                              \
    } } while (0)

    GSTAGE(0, 0);

    for (int s = 0; s < 4; ++s) {
        const int cur = s & 1;
        if (s + 1 < 4) {
            GSTAGE((s + 1) & 1, (s + 1) * 64);
            asm volatile("s_waitcnt vmcnt(6) lgkmcnt(0)" ::: "memory");
        } else {
            asm volatile("s_waitcnt vmcnt(0) lgkmcnt(0)" ::: "memory");
        }
        __builtin_amdgcn_s_barrier();
        __builtin_amdgcn_sched_barrier(0);

        const unsigned short* Ab = As + cur * 4096;
        const unsigned short* Bb = Bs + cur * 8192;
        bf16x8 aF[2][2], bF[2][4];
#pragma unroll
        for (int ks = 0; ks < 2; ++ks) {
#pragma unroll
            for (int mt = 0; mt < 2; ++mt) {
                const int mm = wm + mt * 16 + ml;
                aF[ks][mt] = *(const bf16x8*)(Ab + (mm * 8 + ((ks * 4 + q) ^ (mm & 7))) * 8);
            }
#pragma unroll
            for (int nt = 0; nt < 4; ++nt) {
                const int nn = wn + nt * 16 + ml;
                bF[ks][nt] = *(const bf16x8*)(Bb + (nn * 8 + ((ks * 4 + q) ^ (nn & 7))) * 8);
            }
        }
#pragma unroll
        for (int ks = 0; ks < 2; ++ks)
            for (int mt = 0; mt < 2; ++mt)
                for (int nt = 0; nt < 4; ++nt)
                    acc[mt][nt] = __builtin_amdgcn_mfma_f32_16x16x32_bf16(
                        aF[ks][mt], bF[ks][nt], acc[mt][nt], 0, 0, 0);

        asm volatile("s_waitcnt lgkmcnt(0)" ::: "memory");
        __builtin_amdgcn_s_barrier();
    }
#undef GSTAGE

    for (int mt = 0; mt < 2; ++mt)
        for (int nt = 0; nt < 4; ++nt) {
            const int gn = n0 + wn + nt * 16 + ml;
            for (int r = 0; r < 4; ++r) {
                const int gm = m0 + wm + mt * 16 + q * 4 + r;
                C[(size_t)gm * 16384 + gn] = f2bf(acc[mt][nt][r]);
            }
        }
}

// ---------------------------------------------------------------------------
// FUSED mask + PV, r5's proven LDS-staged loop RE-TILED FOR 4 BLOCKS/CU.
//   out[b,i,:] = (sum_j adj? exp2(e_ij) * h[b,j,:]) / (sum_j adj? exp2(e_ij))
//
// ROUND-10: the only lever that ever moved this kernel was independent
// blocks/CU (r4->r5: 1->2 blk/CU = 61->46us); r8/r9 proved reg-direct B is
// strictly worse than global_load_lds staging.  So: keep r5's loop verbatim
// (Hs dbuf staging, counted vmcnt, raw barriers) and split the o-dimension
// across 2 blocks (each owns 128 of 256 h-rows): Hs 16KB dbuf (j-step 32),
// Ps 2x32x40, LDS ~30KB, grid 1024, 256 thr (4 waves: 2m x 2o) ->
// 4 independent blocks/CU whose barrier stalls interleave.
// Masks: r7 coalesced register prologue (4 u32/thread, no adj in loop).
// Softmax: unnormalized + divide-at-end (r6 math, numerics proven).
// XCD decode: b = ((bid&7)<<1)|(slot>>6) -> 2 batches/XCD; both o-halves of
// the same (b,i0) land on the same XCD so the duplicated adj row is L2-hit.
// ---------------------------------------------------------------------------
__global__ __launch_bounds__(256) void maskpv_kernel(
    const int* __restrict__ adj,
    const float* __restrict__ el2,
    const float* __restrict__ er2,
    const unsigned short* __restrict__ hT,   // 256 x 16384 (row stride 16384)
    float* __restrict__ out)
{
    __shared__ float er_s[1024];                                  //  4 KB
    __shared__ float s_s[32];
    __shared__ __align__(16) unsigned short Hs[2 * 128 * 32];     // 16 KB
    __shared__ __align__(16) unsigned short Ps[2 * 32 * 40];      //  5 KB

    const int tid = threadIdx.x;
    const int w = tid >> 6, l = tid & 63;
    const int q = l >> 4, ml = l & 15;
    const int wm = (w >> 1) * 16;       // row half: 0 | 16
    const int wn = (w & 1) * 64;        // o quarter within this block's half

    const int bid = blockIdx.x;
    const int slot = bid >> 3;                        // 0..127
    const int b = ((bid & 7) << 1) | (slot >> 6);     // 2 batches per XCD
    const int rem = slot & 63;
    const int i0 = (rem >> 1) * 32;
    const int oh = rem & 1;                           // o-half: 0 | 1

    const int ib = tid >> 3;            // P-row this thread builds (0..31)
    const int js = (tid & 7) * 4;       // col offset within 32-window
    const int rg = (b << 10) + i0 + ib;
    const float el2i = el2[rg];

    // hb points at this batch's columns; row index adds oh*128
    const unsigned short* hb = hT + (size_t)b * 1024 + (size_t)oh * 128 * 16384;

// stage 8 KB: 512 chunks of 16B, 256 threads -> 2 gload/thread
#define STAGE(BI, T) do {                                                     \
    const int jb_ = (T) * 32;                                                 \
    _Pragma("unroll")                                                         \
    for (int c_ = 0; c_ < 2; ++c_) {                                          \
        const int cb_ = c_ * 256 + tid;                                       \
        const int r_ = cb_ >> 2;                                              \
        const int cc_ = (cb_ & 3) ^ ((r_ >> 1) & 3);                          \
        gload_lds16(hb + (size_t)r_ * 16384 + jb_ + cc_ * 8,                  \
                    Hs + (BI) * 4096 + (cb_ << 3));                           \
    } } while (0)

    // issue first H tile now; lands while er_s/mask prologue run
    STAGE(0, 0);

    // er_s init: 256 threads x float4
    *(float4*)(er_s + tid * 4) = *(const float4*)(er2 + (b << 10) + tid * 4);

    // ---- PROLOGUE: coalesced adj -> 128 mask bits in 4 registers ----
    // window t (32 cols): bits (t&7)*4 .. +3 of mw[t>>3]
    const int* arow = adj + (size_t)rg * 1024 + js;
    unsigned mw[4] = {0u, 0u, 0u, 0u};
#pragma unroll
    for (int bt = 0; bt < 4; ++bt) {
        int4 av[8];
#pragma unroll
        for (int i = 0; i < 8; ++i)
            av[i] = *(const int4*)(arow + (bt * 8 + i) * 32);
        unsigned acc_bits = 0;
#pragma unroll
        for (int i = 0; i < 8; ++i) {
            const unsigned bits =
                (av[i].x > 0 ? 1u : 0u) | (av[i].y > 0 ? 2u : 0u) |
                (av[i].z > 0 ? 4u : 0u) | (av[i].w > 0 ? 8u : 0u);
            acc_bits |= bits << (i * 4);
        }
        mw[bt] = acc_bits;
    }

    asm volatile("s_waitcnt lgkmcnt(0)" ::: "memory");
    __builtin_amdgcn_s_barrier();

    f32x4 acc[4];
#pragma unroll
    for (int j = 0; j < 4; ++j) {
        f32x4 z = {0.f, 0.f, 0.f, 0.f};
        acc[j] = z;
    }
    float s0 = 0.f, s1 = 0.f, s2 = 0.f, s3 = 0.f;

// build P' = masked exp2(e) (unnormalized); accumulate the denominator from
// the SAME bf16-rounded values (masked entries contribute exactly 0)
#define BUILDR(BI, T) do {                                                    \
    const float4 ev_ = *(const float4*)(er_s + (T) * 32 + js);                \
    const unsigned mv_ = (mw[(T) >> 3] >> (((T) & 7) * 4)) & 0xFu;            \
    float e0_ = el2i + ev_.x; e0_ = fmaxf(e0_, ALPHA * e0_);                  \
    float e1_ = el2i + ev_.y; e1_ = fmaxf(e1_, ALPHA * e1_);                  \
    float e2_ = el2i + ev_.z; e2_ = fmaxf(e2_, ALPHA * e2_);                  \
    float e3_ = el2i + ev_.w; e3_ = fmaxf(e3_, ALPHA * e3_);                  \
    ushort4 pv_;                                                              \
    pv_.x = (mv_ & 1u) ? f2bf(exp2f(e0_)) : (unsigned short)0;                \
    pv_.y = (mv_ & 2u) ? f2bf(exp2f(e1_)) : (unsigned short)0;                \
    pv_.z = (mv_ & 4u) ? f2bf(exp2f(e2_)) : (unsigned short)0;                \
    pv_.w = (mv_ & 8u) ? f2bf(exp2f(e3_)) : (unsigned short)0;                \
    s0 += __uint_as_float((unsigned)pv_.x << 16);                             \
    s1 += __uint_as_float((unsigned)pv_.y << 16);                             \
    s2 += __uint_as_float((unsigned)pv_.z << 16);                             \
    s3 += __uint_as_float((unsigned)pv_.w << 16);                             \
    *(ushort4*)(Ps + (BI) * 1280 + ib * 40 + js) = pv_;                       \
    } while (0)

// K=32 step: one A-fragment, 4 MFMA (o-span 64 per wave)
#define COMPUTE(BI) do {                                                      \
    const bf16x8 aF_ = *(const bf16x8*)(Ps + (BI) * 1280 +                    \
                                        (wm + ml) * 40 + q * 8);              \
    bf16x8 bF_[4];                                                            \
    _Pragma("unroll")                                                         \
    for (int nt_ = 0; nt_ < 4; ++nt_) {                                       \
        const int oc_ = wn + nt_ * 16 + ml;                                   \
        const int sl_ = q ^ ((oc_ >> 1) & 3);                                 \
        bF_[nt_] = *(const bf16x8*)(Hs + (BI) * 4096 + oc_ * 32 + sl_ * 8);   \
    }                                                                         \
    __builtin_amdgcn_s_setprio(1);                                            \
    _Pragma("unroll")                                                         \
    for (int nt_ = 0; nt_ < 4; ++nt_)                                         \
        acc[nt_] = __builtin_amdgcn_mfma_f32_16x16x32_bf16(                   \
            aF_, bF_[nt_], acc[nt_], 0, 0, 0);                                \
    __builtin_amdgcn_s_setprio(0);                                            \
    } while (0)

#pragma unroll
    for (int t = 0; t < 32; ++t) {
        const int cur = t & 1;
        if (t + 1 < 32) STAGE((t + 1) & 1, t + 1);
        BUILDR(cur, t);
        if (t + 1 < 32)
            asm volatile("s_waitcnt vmcnt(2) lgkmcnt(0)" ::: "memory");
        else
            asm volatile("s_waitcnt vmcnt(0) lgkmcnt(0)" ::: "memory");
        __builtin_amdgcn_s_barrier();
        __builtin_amdgcn_sched_barrier(0);
        COMPUTE(cur);
        asm volatile("s_waitcnt lgkmcnt(0)" ::: "memory");
        __builtin_amdgcn_s_barrier();
    }

#undef STAGE
#undef BUILDR
#undef COMPUTE

    // ---- denominator: 8 threads per row -> s_s[ib] ----
    float ssum = (s0 + s1) + (s2 + s3);
#pragma unroll
    for (int off = 1; off <= 4; off <<= 1) ssum += __shfl_xor(ssum, off);
    if ((tid & 7) == 0) s_s[ib] = ssum;
    __syncthreads();

    // D layout: col=lane&15, row=(lane>>4)*4+reg.  Scale by 1/s, store.
    float* ob = out + (size_t)b * 262144 + oh * 128;
    float rinv[4];
#pragma unroll
    for (int r = 0; r < 4; ++r) rinv[r] = 1.0f / s_s[wm + q * 4 + r];
#pragma unroll
    for (int nt = 0; nt < 4; ++nt) {
        const int gn = wn + nt * 16 + ml;
#pragma unroll
        for (int r = 0; r < 4; ++r) {
            const int gm = i0 + wm + q * 4 + r;
            ob[(size_t)gm * 256 + gn] = acc[nt][r] * rinv[r];
        }
    }
}

// ---------------------------------------------------------------------------
// Workspace (~17 MB):
//   Wtbf (bf16) @ 0        : 131072
//   wa   (f32)  @ 131072   : 2048
//   xbf  (bf16) @ 133120   : 8388608   (16384 x 256)
//   h_T  (bf16) @ 8521728  : 8388608   (256 x 16384)
//   el2  (f32)  @ 16910336 : 65536    (log2-scaled)
//   er2  (f32)  @ 16975872 : 65536    (log2-scaled)
// ---------------------------------------------------------------------------
extern "C" void kernel_launch(void* const* d_in, const int* in_sizes, int n_in,
                              void* d_out, int out_size, void* d_ws, size_t ws_size,
                              hipStream_t stream) {
    const float* x   = (const float*)d_in[0];   // (16,1024,256) fp32
    const int*   adj = (const int*)d_in[1];     // (16,1024,1024) int32
    const float* W   = (const float*)d_in[2];   // (256,256) fp32
    const float* a   = (const float*)d_in[3];   // (512,1) fp32
    float* out = (float*)d_out;                 // (16,1024,256) fp32

    char* ws = (char*)d_ws;
    unsigned short* Wtbf  = (unsigned short*)(ws);
    float* wa             = (float*)(ws + 131072);
    unsigned short* xbf   = (unsigned short*)(ws + 133120);
    unsigned short* h_T   = (unsigned short*)(ws + 8521728);
    float* el             = (float*)(ws + 16910336);
    float* er             = (float*)(ws + 16975872);

    wt_wa_kernel<<<dim3(257), dim3(256), 0, stream>>>(W, a, Wtbf, wa);

    eler2x_kernel<<<dim3(4096), dim3(256), 0, stream>>>(x, wa, el, er, xbf);

    // h_T (256 x 16384) = Wtbf @ xbf^T
    gemm_h<<<dim3(128, 4), dim3(256), 0, stream>>>(Wtbf, xbf, h_T);

    maskpv_kernel<<<dim3(1024), dim3(256), 0, stream>>>(adj, el, er, h_T, out);
}

// Round 11
// 159.887 us; speedup vs baseline: 1.3557x; 1.0676x over previous
//
#include <hip/hip_runtime.h>
#include <stdint.h>

#define ALPHA 0.2f
#define L2E 1.4426950408889634f

typedef __attribute__((ext_vector_type(8))) short bf16x8;
typedef __attribute__((ext_vector_type(4))) float f32x4;

__device__ __forceinline__ unsigned short f2bf(float f) {
    unsigned int u = __float_as_uint(f);
    u += 0x7fffu + ((u >> 16) & 1u);   // RNE
    return (unsigned short)(u >> 16);
}

__device__ __forceinline__ void gload_lds16(const void* g, void* l) {
    __builtin_amdgcn_global_load_lds(
        (const __attribute__((address_space(1))) unsigned int*)g,
        (__attribute__((address_space(3))) unsigned int*)l, 16, 0, 0);
}

// ---------------------------------------------------------------------------
// Blocks 0..255: Wtbf[o*256+t] = bf16(W[t*256+o]).
// Block 256:     wa[k] = W[k,:]·a_l ; wa[256+k] = W[k,:]·a_r  (fp32).
// ---------------------------------------------------------------------------
__global__ void wt_wa_kernel(const float* __restrict__ W,
                             const float* __restrict__ a,
                             unsigned short* __restrict__ Wtbf,
                             float* __restrict__ wa) {
    const int t = threadIdx.x;
    if (blockIdx.x < 256) {
        const int o = blockIdx.x;
        Wtbf[o * 256 + t] = f2bf(W[t * 256 + o]);
    } else {
        float sl = 0.f, sr = 0.f;
        const float* wr = W + t * 256;
        for (int o = 0; o < 256; ++o) {
            const float wv = wr[o];
            sl += wv * a[o];
            sr += wv * a[256 + o];
        }
        wa[t] = sl;
        wa[256 + t] = sr;
    }
}

// ---------------------------------------------------------------------------
// One wave per row r: el2[r] = (x[r,:]·wa_l)*log2(e), er2 likewise,
// and xbf[r,:] = bf16(x[r,:]).
// ---------------------------------------------------------------------------
__global__ __launch_bounds__(256) void eler2x_kernel(
    const float* __restrict__ x, const float* __restrict__ wa,
    float* __restrict__ el, float* __restrict__ er,
    unsigned short* __restrict__ xbf)
{
    const int w = threadIdx.x >> 6, l = threadIdx.x & 63;
    const int r = blockIdx.x * 4 + w;       // 0..16383
    const float4 xv = *(const float4*)(x + (size_t)r * 256 + l * 4);
    const float4 al = *(const float4*)(wa + l * 4);
    const float4 ar = *(const float4*)(wa + 256 + l * 4);

    ushort4 xb;
    xb.x = f2bf(xv.x); xb.y = f2bf(xv.y); xb.z = f2bf(xv.z); xb.w = f2bf(xv.w);
    *(ushort4*)(xbf + (size_t)r * 256 + l * 4) = xb;

    float sl = xv.x * al.x + xv.y * al.y + xv.z * al.z + xv.w * al.w;
    float sr = xv.x * ar.x + xv.y * ar.y + xv.z * ar.z + xv.w * ar.w;
#pragma unroll
    for (int off = 32; off >= 1; off >>= 1) {
        sl += __shfl_xor(sl, off);
        sr += __shfl_xor(sr, off);
    }
    if (l == 0) { el[r] = sl * L2E; er[r] = sr * L2E; }
}

// ---------------------------------------------------------------------------
// h_T (256 x 16384) = Wtbf (256x256) @ xbf^T.  Flat batched GEMM.
// 64(m) x 128(n) tiles, K-step 64, grid (128,4) = 512 blocks (2/CU).
// 2-phase: double-buffered LDS, counted vmcnt (loads fly across barriers).
// ---------------------------------------------------------------------------
__global__ __launch_bounds__(256) void gemm_h(
    const unsigned short* __restrict__ A,    // Wtbf 256x256
    const unsigned short* __restrict__ Bt,   // xbf 16384x256
    unsigned short* __restrict__ C)          // h_T 256x16384
{
    __shared__ __align__(16) unsigned short As[2 * 64 * 64];    // 16 KB
    __shared__ __align__(16) unsigned short Bs[2 * 128 * 64];   // 32 KB

    const int tid = threadIdx.x;
    const int w = tid >> 6, l = tid & 63;
    const int q = l >> 4, ml = l & 15;
    const int wm = (w >> 1) * 32;
    const int wn = (w & 1) * 64;
    const int m0 = blockIdx.y * 64;
    const int n0 = blockIdx.x * 128;

    f32x4 acc[2][4];
#pragma unroll
    for (int i = 0; i < 2; ++i)
#pragma unroll
        for (int j = 0; j < 4; ++j) {
            f32x4 z = {0.f, 0.f, 0.f, 0.f};
            acc[i][j] = z;
        }

#define GSTAGE(BI, K0) do {                                                   \
    _Pragma("unroll")                                                         \
    for (int c_ = 0; c_ < 2; ++c_) {                                          \
        const int cb_ = c_ * 256 + (w << 6);                                  \
        const int p_ = cb_ + l;                                               \
        const int r_ = p_ >> 3;                                               \
        const int cc_ = (p_ & 7) ^ (r_ & 7);                                  \
        gload_lds16(A + (size_t)(m0 + r_) * 256 + (K0) + cc_ * 8,             \
                    As + (BI) * 4096 + cb_ * 8);                              \
    }                                                                         \
    _Pragma("unroll")                                                         \
    for (int c_ = 0; c_ < 4; ++c_) {                                          \
        const int cb_ = c_ * 256 + (w << 6);                                  \
        const int p_ = cb_ + l;                                               \
        const int r_ = p_ >> 3;                                               \
        const int cc_ = (p_ & 7) ^ (r_ & 7);                                  \
        gload_lds16(Bt + (size_t)(n0 + r_) * 256 + (K0) + cc_ * 8,            \
                    Bs + (BI) * 8192 + cb_ * 8);                              \
    } } while (0)

    GSTAGE(0, 0);

    for (int s = 0; s < 4; ++s) {
        const int cur = s & 1;
        if (s + 1 < 4) {
            GSTAGE((s + 1) & 1, (s + 1) * 64);
            asm volatile("s_waitcnt vmcnt(6) lgkmcnt(0)" ::: "memory");
        } else {
            asm volatile("s_waitcnt vmcnt(0) lgkmcnt(0)" ::: "memory");
        }
        __builtin_amdgcn_s_barrier();
        __builtin_amdgcn_sched_barrier(0);

        const unsigned short* Ab = As + cur * 4096;
        const unsigned short* Bb = Bs + cur * 8192;
        bf16x8 aF[2][2], bF[2][4];
#pragma unroll
        for (int ks = 0; ks < 2; ++ks) {
#pragma unroll
            for (int mt = 0; mt < 2; ++mt) {
                const int mm = wm + mt * 16 + ml;
                aF[ks][mt] = *(const bf16x8*)(Ab + (mm * 8 + ((ks * 4 + q) ^ (mm & 7))) * 8);
            }
#pragma unroll
            for (int nt = 0; nt < 4; ++nt) {
                const int nn = wn + nt * 16 + ml;
                bF[ks][nt] = *(const bf16x8*)(Bb + (nn * 8 + ((ks * 4 + q) ^ (nn & 7))) * 8);
            }
        }
#pragma unroll
        for (int ks = 0; ks < 2; ++ks)
            for (int mt = 0; mt < 2; ++mt)
                for (int nt = 0; nt < 4; ++nt)
                    acc[mt][nt] = __builtin_amdgcn_mfma_f32_16x16x32_bf16(
                        aF[ks][mt], bF[ks][nt], acc[mt][nt], 0, 0, 0);

        asm volatile("s_waitcnt lgkmcnt(0)" ::: "memory");
        __builtin_amdgcn_s_barrier();
    }
#undef GSTAGE

    for (int mt = 0; mt < 2; ++mt)
        for (int nt = 0; nt < 4; ++nt) {
            const int gn = n0 + wn + nt * 16 + ml;
            for (int r = 0; r < 4; ++r) {
                const int gm = m0 + wm + mt * 16 + q * 4 + r;
                C[(size_t)gm * 16384 + gn] = f2bf(acc[mt][nt][r]);
            }
        }
}

// ---------------------------------------------------------------------------
// FUSED mask + PV, r5/r7 geometry + 4-SLOT HALF-TILE RING (depth-2 cover).
//   out[b,i,:] = (sum_j adj? exp2(e_ij) * h[b,j,:]) / (sum_j adj? exp2(e_ij))
//
// ROUND-11 DIAGNOSIS: every depth-1 variant (r3/r5/r6/r7/r10) sits at
// 46-66us with all pipes idle — the staged tile only ever gets one
// BUILD-phase (~200cy) of latency cover before the block-wide vmcnt+barrier,
// exposing ~300-900cy of L2/L3 latency EVERY iteration (r6's depth-1 adj
// load showed the mechanism at +5us).  Fix = the proven T4 discipline: a
// ring of 4 x 16KB half-tiles (256 rows x 32 cols); iter t consumes tiles
// 2t,2t+1 and re-issues 2t+4,2t+5 AFTER the consume-barrier into the freed
// slots.  The pre-compute wait vmcnt(4) covers tiles issued TWO full
// iterations ago (~800cy) — never waits on freshly-issued loads.
// Geometry r5-identical: grid 512, 512 thr (8 waves 2m x 4o), M=32,
// K=64 compute steps, LDS 79KB -> 2 blocks/CU.
// Masks: r7 register prologue.  Softmax: unnormalized, divide-at-end (r6).
// Swizzle pair for 32-col tiles: refcheck'd in r10.
// XCD decode: b = ((bid&7)<<1)|(slot>>5): 2 batches (1 MB h) per XCD L2.
// ---------------------------------------------------------------------------
__global__ __launch_bounds__(512) void maskpv_kernel(
    const int* __restrict__ adj,
    const float* __restrict__ el2,
    const float* __restrict__ er2,
    const unsigned short* __restrict__ hT,   // 256 x 16384 (row stride 16384)
    float* __restrict__ out)
{
    __shared__ float er_s[1024];                                  //  4 KB
    __shared__ float s_s[32];
    __shared__ __align__(16) unsigned short Hs[4 * 256 * 32];     // 64 KB ring
    __shared__ __align__(16) unsigned short Ps[2 * 32 * 72];      //  9 KB

    const int tid = threadIdx.x;
    const int w = tid >> 6, l = tid & 63;
    const int q = l >> 4, ml = l & 15;
    const int wm = (w >> 2) * 16;       // row half: 0 | 16
    const int wn = (w & 3) * 64;        // o quarter: 0..192

    const int bid = blockIdx.x;
    const int slot = bid >> 3;                        // 0..63
    const int b = ((bid & 7) << 1) | (slot >> 5);     // 2 batches per XCD
    const int i0 = (slot & 31) * 32;

    const int ib = tid >> 4;            // P-row this thread builds (0..31)
    const int js = (tid & 15) * 4;      // col offset within 64-window
    const int rg = (b << 10) + i0 + ib;
    const float el2i = el2[rg];

    const unsigned short* hb = hT + (size_t)b * 1024;

// stage one 16 KB half-tile (256 rows x 32 cols) into ring slot S.
// 1024 chunks of 16B, 512 threads -> 2 gload/thread.  Swizzle pair (write
// source / read slot) refcheck'd in r10.
#define STAGE(S, T) do {                                                      \
    const int jb_ = (T) * 32;                                                 \
    _Pragma("unroll")                                                         \
    for (int c_ = 0; c_ < 2; ++c_) {                                          \
        const int cb_ = c_ * 512 + tid;                                       \
        const int r_ = cb_ >> 2;                                              \
        const int cc_ = (cb_ & 3) ^ ((r_ >> 1) & 3);                          \
        gload_lds16(hb + (size_t)r_ * 16384 + jb_ + cc_ * 8,                  \
                    Hs + (S) * 8192 + (cb_ << 3));                            \
    } } while (0)

    // ---- prologue: fill the ring (tiles 0..3 -> slots 0..3), 8 loads ----
    STAGE(0, 0); STAGE(1, 1); STAGE(2, 2); STAGE(3, 3);

    // er_s init
    *(float2*)(er_s + tid * 2) = *(const float2*)(er2 + (b << 10) + tid * 2);

    // ---- adj -> 64 mask bits in 2 registers (r7 coalesced prologue) ----
    const int* arow = adj + (size_t)rg * 1024;
    unsigned mw0 = 0, mw1 = 0;
    {
        int4 av[8];
#pragma unroll
        for (int i = 0; i < 8; ++i)
            av[i] = *(const int4*)(arow + i * 64 + js);
#pragma unroll
        for (int i = 0; i < 8; ++i) {
            const unsigned bits =
                (av[i].x > 0 ? 1u : 0u) | (av[i].y > 0 ? 2u : 0u) |
                (av[i].z > 0 ? 4u : 0u) | (av[i].w > 0 ? 8u : 0u);
            mw0 |= bits << (i * 4);
        }
#pragma unroll
        for (int i = 0; i < 8; ++i)
            av[i] = *(const int4*)(arow + (i + 8) * 64 + js);
#pragma unroll
        for (int i = 0; i < 8; ++i) {
            const unsigned bits =
                (av[i].x > 0 ? 1u : 0u) | (av[i].y > 0 ? 2u : 0u) |
                (av[i].z > 0 ? 4u : 0u) | (av[i].w > 0 ? 8u : 0u);
            mw1 |= bits << (i * 4);
        }
    }

    asm volatile("s_waitcnt lgkmcnt(0)" ::: "memory");
    __builtin_amdgcn_s_barrier();

    f32x4 acc[4];
#pragma unroll
    for (int j = 0; j < 4; ++j) {
        f32x4 z = {0.f, 0.f, 0.f, 0.f};
        acc[j] = z;
    }
    float s0 = 0.f, s1 = 0.f, s2 = 0.f, s3 = 0.f;

// build P' = masked exp2(e) for the t-th 64-col window into Ps[BI];
// denominator accumulated from the SAME bf16-rounded values
#define BUILDR(BI, T) do {                                                    \
    const float4 ev_ = *(const float4*)(er_s + (T) * 64 + js);                \
    const unsigned mv_ =                                                      \
        (((T) < 8) ? (mw0 >> ((T) * 4)) : (mw1 >> (((T) - 8) * 4))) & 0xFu;   \
    float e0_ = el2i + ev_.x; e0_ = fmaxf(e0_, ALPHA * e0_);                  \
    float e1_ = el2i + ev_.y; e1_ = fmaxf(e1_, ALPHA * e1_);                  \
    float e2_ = el2i + ev_.z; e2_ = fmaxf(e2_, ALPHA * e2_);                  \
    float e3_ = el2i + ev_.w; e3_ = fmaxf(e3_, ALPHA * e3_);                  \
    ushort4 pv_;                                                              \
    pv_.x = (mv_ & 1u) ? f2bf(exp2f(e0_)) : (unsigned short)0;                \
    pv_.y = (mv_ & 2u) ? f2bf(exp2f(e1_)) : (unsigned short)0;                \
    pv_.z = (mv_ & 4u) ? f2bf(exp2f(e2_)) : (unsigned short)0;                \
    pv_.w = (mv_ & 8u) ? f2bf(exp2f(e3_)) : (unsigned short)0;                \
    s0 += __uint_as_float((unsigned)pv_.x << 16);                             \
    s1 += __uint_as_float((unsigned)pv_.y << 16);                             \
    s2 += __uint_as_float((unsigned)pv_.z << 16);                             \
    s3 += __uint_as_float((unsigned)pv_.w << 16);                             \
    *(ushort4*)(Ps + (BI) * 2304 + ib * 72 + js) = pv_;                       \
    } while (0)

// K=64 step t: A-fragments from Ps[BI]; B-fragments from ring slots
// (2t)&3 (ks=0) and (2t+1)&3 (ks=1); read swizzle sl = q ^ ((oc>>1)&3).
#define COMPUTE(BI, T) do {                                                   \
    bf16x8 aF_[2], bF_[2][4];                                                 \
    _Pragma("unroll")                                                         \
    for (int ks_ = 0; ks_ < 2; ++ks_)                                         \
        aF_[ks_] = *(const bf16x8*)(Ps + (BI) * 2304 +                        \
                                    (wm + ml) * 72 + ks_ * 32 + q * 8);       \
    _Pragma("unroll")                                                         \
    for (int ks_ = 0; ks_ < 2; ++ks_) {                                       \
        const int sb_ = ((2 * (T) + ks_) & 3) * 8192;                         \
        _Pragma("unroll")                                                     \
        for (int nt_ = 0; nt_ < 4; ++nt_) {                                   \
            const int oc_ = wn + nt_ * 16 + ml;                               \
            const int sl_ = q ^ ((oc_ >> 1) & 3);                             \
            bF_[ks_][nt_] = *(const bf16x8*)(Hs + sb_ + oc_ * 32 + sl_ * 8);  \
        }                                                                     \
    }                                                                         \
    __builtin_amdgcn_s_setprio(1);                                            \
    _Pragma("unroll")                                                         \
    for (int ks_ = 0; ks_ < 2; ++ks_)                                         \
        _Pragma("unroll")                                                     \
        for (int nt_ = 0; nt_ < 4; ++nt_)                                     \
            acc[nt_] = __builtin_amdgcn_mfma_f32_16x16x32_bf16(               \
                aF_[ks_], bF_[ks_][nt_], acc[nt_], 0, 0, 0);                  \
    __builtin_amdgcn_s_setprio(0);                                            \
    } while (0)

#pragma unroll
    for (int t = 0; t < 16; ++t) {
        BUILDR(t & 1, t);
        // tiles 2t,2t+1 were issued 2 iterations ago; the newest 4 loads
        // (tiles 2t+2,2t+3) may remain in flight.
        if (t < 15)
            asm volatile("s_waitcnt vmcnt(4) lgkmcnt(0)" ::: "memory");
        else
            asm volatile("s_waitcnt vmcnt(0) lgkmcnt(0)" ::: "memory");
        __builtin_amdgcn_s_barrier();
        __builtin_amdgcn_sched_barrier(0);
        COMPUTE(t & 1, t);
        asm volatile("s_waitcnt lgkmcnt(0)" ::: "memory");
        __builtin_amdgcn_s_barrier();
        // refill the two slots just consumed (safe: all waves passed the
        // consume-barrier; data lands only after issue)
        if (t <= 13) {
            STAGE((2 * t + 4) & 3, 2 * t + 4);
            STAGE((2 * t + 5) & 3, 2 * t + 5);
        }
    }

#undef STAGE
#undef BUILDR
#undef COMPUTE

    // ---- denominator: 16 threads per row -> s_s[ib] ----
    float ssum = (s0 + s1) + (s2 + s3);
#pragma unroll
    for (int off = 1; off <= 8; off <<= 1) ssum += __shfl_xor(ssum, off);
    if ((tid & 15) == 0) s_s[ib] = ssum;
    __syncthreads();

    // D layout: col=lane&15, row=(lane>>4)*4+reg.  Scale by 1/s, store.
    float* ob = out + (size_t)b * 262144;
    float rinv[4];
#pragma unroll
    for (int r = 0; r < 4; ++r) rinv[r] = 1.0f / s_s[wm + q * 4 + r];
#pragma unroll
    for (int nt = 0; nt < 4; ++nt) {
        const int gn = wn + nt * 16 + ml;
#pragma unroll
        for (int r = 0; r < 4; ++r) {
            const int gm = i0 + wm + q * 4 + r;
            ob[(size_t)gm * 256 + gn] = acc[nt][r] * rinv[r];
        }
    }
}

// ---------------------------------------------------------------------------
// Workspace (~17 MB):
//   Wtbf (bf16) @ 0        : 131072
//   wa   (f32)  @ 131072   : 2048
//   xbf  (bf16) @ 133120   : 8388608   (16384 x 256)
//   h_T  (bf16) @ 8521728  : 8388608   (256 x 16384)
//   el2  (f32)  @ 16910336 : 65536    (log2-scaled)
//   er2  (f32)  @ 16975872 : 65536    (log2-scaled)
// ---------------------------------------------------------------------------
extern "C" void kernel_launch(void* const* d_in, const int* in_sizes, int n_in,
                              void* d_out, int out_size, void* d_ws, size_t ws_size,
                              hipStream_t stream) {
    const float* x   = (const float*)d_in[0];   // (16,1024,256) fp32
    const int*   adj = (const int*)d_in[1];     // (16,1024,1024) int32
    const float* W   = (const float*)d_in[2];   // (256,256) fp32
    const float* a   = (const float*)d_in[3];   // (512,1) fp32
    float* out = (float*)d_out;                 // (16,1024,256) fp32

    char* ws = (char*)d_ws;
    unsigned short* Wtbf  = (unsigned short*)(ws);
    float* wa             = (float*)(ws + 131072);
    unsigned short* xbf   = (unsigned short*)(ws + 133120);
    unsigned short* h_T   = (unsigned short*)(ws + 8521728);
    float* el             = (float*)(ws + 16910336);
    float* er             = (float*)(ws + 16975872);

    wt_wa_kernel<<<dim3(257), dim3(256), 0, stream>>>(W, a, Wtbf, wa);

    eler2x_kernel<<<dim3(4096), dim3(256), 0, stream>>>(x, wa, el, er, xbf);

    // h_T (256 x 16384) = Wtbf @ xbf^T
    gemm_h<<<dim3(128, 4), dim3(256), 0, stream>>>(Wtbf, xbf, h_T);

    maskpv_kernel<<<dim3(512), dim3(512), 0, stream>>>(adj, el, er, h_T, out);
}